// Round 3
// baseline (288.967 us; speedup 1.0000x reference)
//
#include <hip/hip_runtime.h>
#include <math.h>
#include <stdint.h>

#define N_ANCH 49104
#define NQ (N_ANCH / 4)      // 12276 float4 quads per class column
#define NCLS 80
#define KDET 100
#define NBINS 1024
#define NSEG 8
#define CAP 512              // candidate cap per class chunk (== sort size == TPB)
#define TARGET 384           // min candidates above cutoff (need ~112 for 100 keeps)
#define SROWS 256            // bitmatrix rows built per scan phase
#define MWMAX 8              // CAP/64 live-mask words
#define TPB 512
#define TROWS 128

// ws layout (bytes)
#define ST_BYTES   ((size_t)NCLS * N_ANCH * 4)                 // 15,713,280
#define HPART_OFF  ST_BYTES
#define HPART_BYTES ((size_t)NCLS * NSEG * NBINS * 4)          // 2,621,440
#define CNT_OFF    (HPART_OFF + HPART_BYTES)                   // 18,334,720
#define LIST_OFF   (CNT_OFF + 320)                             // 18,335,040 (8B aligned)
#define WS_NEED    (LIST_OFF + (size_t)NCLS * CAP * 8)         // 18,662,720

// ---------------- transpose [N,C] -> [C,N] so per-class reads are coalesced ----------------
__global__ __launch_bounds__(256) void transpose_scores(const float* __restrict__ scores,
                                                        float* __restrict__ st) {
    __shared__ float tile[TROWS][NCLS + 1];
    const int n0 = blockIdx.x * TROWS;
    for (int i = threadIdx.x; i < TROWS * NCLS; i += blockDim.x) {
        int j = i / NCLS, c = i - j * NCLS;
        int n = n0 + j;
        tile[j][c] = (n < N_ANCH) ? scores[(size_t)n * NCLS + c] : -1.0f;
    }
    __syncthreads();
    for (int i = threadIdx.x; i < TROWS * NCLS; i += blockDim.x) {
        int c = i / TROWS, j = i - c * TROWS;
        int n = n0 + j;
        if (n < N_ANCH) st[(size_t)c * N_ANCH + n] = tile[j][c];
    }
}

// ---------------- 640 blocks: per-(class,segment) partial histograms ----------------
__global__ __launch_bounds__(256) void hist_kernel(const float* __restrict__ st,
                                                   int* __restrict__ hpart,
                                                   int* __restrict__ cnt) {
    const int x = blockIdx.x, c = x >> 3, s = x & 7;
    const int tid = threadIdx.x;
    __shared__ int hist[NBINS];
    for (int b = tid; b < NBINS; b += 256) hist[b] = 0;
    __syncthreads();
    const float4* col4 = (const float4*)(st + (size_t)c * N_ANCH);
    const int q0 = (s * NQ) / NSEG, q1 = ((s + 1) * NQ) / NSEG;
    for (int q = q0 + tid; q < q1; q += 256) {
        float4 s4 = col4[q];
        float ss[4] = {s4.x, s4.y, s4.z, s4.w};
#pragma unroll
        for (int u = 0; u < 4; u++) {
            float sc = ss[u];
            if (sc > 0.05f) {
                int b = (int)(sc * 1024.0f);
                b = b < 0 ? 0 : (b > NBINS - 1 ? NBINS - 1 : b);
                atomicAdd(&hist[b], 1);
            }
        }
    }
    __syncthreads();
    int* hp = hpart + (size_t)x * NBINS;
    for (int b = tid; b < NBINS; b += 256) hp[b] = hist[b];
    if (s == 0 && tid == 0) cnt[c] = 0;   // counters used by collect (next dispatch)
}

// ---------------- 640 blocks: cutoff + push candidate keys to per-class lists ----------------
__global__ __launch_bounds__(256) void collect_kernel(const float* __restrict__ st,
                                                      const int* __restrict__ hpart,
                                                      int* __restrict__ cnt,
                                                      uint64_t* __restrict__ list) {
    const int x = blockIdx.x, c = x >> 3, s = x & 7;
    const int tid = threadIdx.x;
    __shared__ int hist[NBINS];
    __shared__ int s_cut;
    for (int b = tid; b < NBINS; b += 256) {
        int t = 0;
#pragma unroll
        for (int sg = 0; sg < NSEG; sg++) t += hpart[(size_t)(c * NSEG + sg) * NBINS + b];
        hist[b] = t;
    }
    __syncthreads();
    if (tid == 0) {
        int cut = NBINS, tot = 0;
        while (cut > 0 && tot < TARGET) { cut--; tot += hist[cut]; }
        while (tot > CAP && cut < NBINS) { tot -= hist[cut]; cut++; }   // guarantee <= CAP pushes
        s_cut = cut;
    }
    __syncthreads();
    const int cut = s_cut;
    const float4* col4 = (const float4*)(st + (size_t)c * N_ANCH);
    const int q0 = (s * NQ) / NSEG, q1 = ((s + 1) * NQ) / NSEG;
    uint64_t* lst = list + (size_t)c * CAP;
    for (int q = q0 + tid; q < q1; q += 256) {
        float4 s4 = col4[q];
        float ss[4] = {s4.x, s4.y, s4.z, s4.w};
#pragma unroll
        for (int u = 0; u < 4; u++) {
            float sc = ss[u];
            if (sc > 0.05f) {
                int b = (int)(sc * 1024.0f);
                b = b < 0 ? 0 : (b > NBINS - 1 ? NBINS - 1 : b);
                if (b >= cut) {
                    int p = atomicAdd(&cnt[c], 1);
                    if (p < CAP) {
                        uint32_t bits = __float_as_uint(sc);
                        lst[p] = ((uint64_t)(~bits) << 16) | (uint64_t)(4 * q + u);
                    }
                }
            }
        }
    }
}

// ---------------- 80 blocks: sort -> bitmatrix -> register-mask scan (+ exact fallback) ----------------
__global__ __launch_bounds__(TPB) void nms_final(const float* __restrict__ st,
                                                 const float* __restrict__ boxes,
                                                 const int* __restrict__ hpart,
                                                 const int* __restrict__ cnt,
                                                 const uint64_t* __restrict__ list,
                                                 float* __restrict__ out) {
    const int c = blockIdx.x, tid = threadIdx.x;
    __shared__ uint64_t keys[CAP];
    __shared__ float4   rbox[CAP];
    __shared__ float    ra[CAP], rs[CAP];
    __shared__ uint64_t smat[SROWS * MWMAX];
    __shared__ uint64_t lwbuf[MWMAX];
    __shared__ float4   kbox[KDET];
    __shared__ float    kar[KDET], ksc[KDET];
    __shared__ int      hist[NBINS];
    __shared__ int      s_kc, s_lo, s_newlo, s_cnt2;

    int kc = 0;
    int M = min(cnt[c], CAP);
    keys[tid] = (tid < M) ? list[(size_t)c * CAP + tid] : ~0ull;
    bool have_hist = false;
    int lo = NBINS;

    for (;;) {
        __syncthreads();
        // bitonic sort ascending: (~score, anchor) => score desc, index asc on ties
        for (int k = 2; k <= CAP; k <<= 1)
            for (int j = k >> 1; j > 0; j >>= 1) {
                int t = tid, ixj = t ^ j;
                if (ixj > t) {
                    uint64_t a = keys[t], b = keys[ixj];
                    if ((a > b) == ((t & k) == 0)) { keys[t] = b; keys[ixj] = a; }
                }
                __syncthreads();
            }
        // gather rank-ordered candidate data
        if (tid < M) {
            uint64_t key = keys[tid];
            int n = (int)(key & 0xFFFFull);
            uint32_t bits = ~((uint32_t)(key >> 16));
            float4 bx = *(const float4*)(boxes + (size_t)n * 4);
            rbox[tid] = bx;
            ra[tid] = (bx.z - bx.x) * (bx.w - bx.y);
            rs[tid] = __uint_as_float(bits);
        }
        __syncthreads();
        // filter vs previously-kept; live-mask via ballot
        {
            bool alive = (tid < M);
            if (alive && kc > 0) {
                float4 b = rbox[tid]; float arb = ra[tid];
                for (int k2 = 0; k2 < kc; k2++) {
                    float4 kb = kbox[k2];
                    float ix1 = fmaxf(kb.x, b.x), iy1 = fmaxf(kb.y, b.y);
                    float ix2 = fminf(kb.z, b.z), iy2 = fminf(kb.w, b.w);
                    float inter = fmaxf(ix2 - ix1, 0.0f) * fmaxf(iy2 - iy1, 0.0f);
                    float iou = inter / (kar[k2] + arb - inter + 1e-8f);
                    if (iou > 0.5f) { alive = false; break; }
                }
            }
            uint64_t bal = __ballot(alive);
            if ((tid & 63) == 0) lwbuf[tid >> 6] = bal;
        }
        __syncthreads();
        // phased scan: build suppressor rows [r0, r0+SROWS), thread-0 walks with register masks
        const int MW = (M + 63) >> 6;
        int r0 = 0;
        while (r0 < M && kc < KDET) {
            const int rend = min(r0 + SROWS, M);
            {
                const int wid = tid >> 6, lane = tid & 63;
                for (int i = r0 + wid; i < rend; i += TPB / 64) {
                    float4 bi = rbox[i]; float ari = ra[i];
                    for (int w = i >> 6; w < MW; w++) {
                        int jj = (w << 6) + lane;
                        bool bit = false;
                        if (jj > i && jj < M) {
                            float4 bj = rbox[jj];
                            float ix1 = fmaxf(bi.x, bj.x), iy1 = fmaxf(bi.y, bj.y);
                            float ix2 = fminf(bi.z, bj.z), iy2 = fminf(bi.w, bj.w);
                            float inter = fmaxf(ix2 - ix1, 0.0f) * fmaxf(iy2 - iy1, 0.0f);
                            float iou = inter / (ari + ra[jj] - inter + 1e-8f);
                            bit = iou > 0.5f;
                        }
                        uint64_t bal = __ballot(bit);
                        if (lane == 0) smat[(size_t)(i - r0) * MWMAX + w] = bal;
                    }
                }
            }
            __syncthreads();
            if (tid == 0) {
                uint64_t lw[MWMAX];
#pragma unroll
                for (int w = 0; w < MWMAX; w++) lw[w] = lwbuf[w];
                int kcl = kc;
                for (int w = r0 >> 6; w < MW && kcl < KDET; w++) {
                    int hib = rend - (w << 6);
                    if (hib <= 0) break;
                    uint64_t mask = (hib >= 64) ? ~0ull : ((1ull << hib) - 1ull);
                    for (;;) {
                        uint64_t lv = lw[w] & mask;
                        if (!lv) break;
                        int b = __ffsll((unsigned long long)lv) - 1;
                        int i = (w << 6) + b;
                        lw[w] &= ~(1ull << b);
                        kbox[kcl] = rbox[i]; kar[kcl] = ra[i]; ksc[kcl] = rs[i];
                        kcl++;
                        if (kcl >= KDET) break;
                        const uint64_t* row = &smat[(size_t)(i - r0) * MWMAX];
                        for (int ww = w; ww < MW; ww++) {
                            uint64_t rw = row[ww];
                            if (rw) lw[ww] &= ~rw;
                        }
                    }
                }
#pragma unroll
                for (int w = 0; w < MWMAX; w++) lwbuf[w] = lw[w];
                s_kc = kcl;
            }
            __syncthreads();
            kc = s_kc;
            r0 = rend;
        }
        if (kc >= KDET) break;
        // exact fallback: continue into lower score bins (never triggered on this input)
        if (!have_hist) {
            for (int b = tid; b < NBINS; b += TPB) {
                int t = 0;
#pragma unroll
                for (int sg = 0; sg < NSEG; sg++) t += hpart[(size_t)(c * NSEG + sg) * NBINS + b];
                hist[b] = t;
            }
            __syncthreads();
            if (tid == 0) {
                int cut = NBINS, tot = 0;
                while (cut > 0 && tot < TARGET) { cut--; tot += hist[cut]; }
                while (tot > CAP && cut < NBINS) { tot -= hist[cut]; cut++; }
                s_lo = cut;
            }
            __syncthreads();
            lo = s_lo;
            have_hist = true;
        }
        if (lo <= 0) break;
        if (tid == 0) {
            int nl = lo, tot = 0;
            while (nl > 0 && tot + hist[nl - 1] <= CAP) { nl--; tot += hist[nl]; }
            if (nl == lo) nl = lo - 1;
            s_newlo = nl; s_cnt2 = 0;
        }
        __syncthreads();
        const int nlo = s_newlo;
        const float4* col4 = (const float4*)(st + (size_t)c * N_ANCH);
        for (int q = tid; q < NQ; q += TPB) {
            float4 s4 = col4[q];
            float ss[4] = {s4.x, s4.y, s4.z, s4.w};
#pragma unroll
            for (int u = 0; u < 4; u++) {
                float sc = ss[u];
                if (sc > 0.05f) {
                    int b = (int)(sc * 1024.0f);
                    b = b < 0 ? 0 : (b > NBINS - 1 ? NBINS - 1 : b);
                    if (b >= nlo && b < lo) {
                        int p = atomicAdd(&s_cnt2, 1);
                        if (p < CAP) {
                            uint32_t bits = __float_as_uint(sc);
                            keys[p] = ((uint64_t)(~bits) << 16) | (uint64_t)(4 * q + u);
                        }
                    }
                }
            }
        }
        __syncthreads();
        M = min(s_cnt2, CAP);
        if (tid >= M) keys[tid] = ~0ull;
        lo = nlo;
    }
    __syncthreads();

    // outputs: [scores | classes | boxes | valids] as float32
    float* o_sc = out;
    float* o_cl = out + NCLS * KDET;
    float* o_bx = out + 2 * NCLS * KDET;
    float* o_va = out + 6 * NCLS * KDET;
    for (int k = tid; k < KDET; k += TPB) {
        bool valid = k < kc;
        o_sc[c * KDET + k] = valid ? ksc[k] : 0.0f;
        o_cl[c * KDET + k] = (float)c;
        o_va[c * KDET + k] = valid ? 1.0f : 0.0f;
        float4 bo;
        if (valid) bo = kbox[k];
        else { bo.x = 0.0f; bo.y = 0.0f; bo.z = 0.0f; bo.w = 0.0f; }
        *(float4*)(o_bx + ((size_t)(c * KDET + k)) * 4) = bo;
    }
}

// ---------------- fallback monolith (round-2 kernel, proven exact) for small ws ----------------
__global__ __launch_bounds__(TPB) void nms_mono(const float* __restrict__ st,
                                                const float* __restrict__ boxes,
                                                float* __restrict__ out) {
    const int c = blockIdx.x;
    const int tid = threadIdx.x;
    const float* col = st + (size_t)c * N_ANCH;
    const float4* col4 = (const float4*)col;

    __shared__ int      hist[NBINS];
    __shared__ float4   rbox[CAP];
    __shared__ float    ra[CAP], rs[CAP];
    __shared__ uint64_t uni[CAP * 8];
    __shared__ float4   kbox[KDET];
    __shared__ float    kar[KDET], ksc[KDET];
    __shared__ uint64_t lw[8];
    __shared__ int      s_cnt, s_lo, s_kc;

    uint64_t* keys = uni;
    uint64_t* smat = uni;

    for (int b = tid; b < NBINS; b += TPB) hist[b] = 0;
    __syncthreads();
    for (int q = tid; q < NQ; q += TPB) {
        float4 s4 = col4[q];
        float ss[4] = {s4.x, s4.y, s4.z, s4.w};
#pragma unroll
        for (int u = 0; u < 4; u++) {
            float s = ss[u];
            if (s > 0.05f) {
                int b = (int)(s * 1024.0f);
                b = b < 0 ? 0 : (b > NBINS - 1 ? NBINS - 1 : b);
                atomicAdd(&hist[b], 1);
            }
        }
    }
    __syncthreads();

    int kc = 0;
    int hi = NBINS;
    while (hi > 0 && kc < KDET) {
        if (tid == 0) {
            int lo = hi, tot = 0;
            while (lo > 0 && tot + hist[lo - 1] <= CAP) { lo--; tot += hist[lo]; }
            if (lo == hi) lo = hi - 1;
            s_lo = lo; s_cnt = 0;
        }
        __syncthreads();
        const int lo = s_lo;
        for (int q = tid; q < NQ; q += TPB) {
            float4 s4 = col4[q];
            float ss[4] = {s4.x, s4.y, s4.z, s4.w};
#pragma unroll
            for (int u = 0; u < 4; u++) {
                float s = ss[u];
                if (s > 0.05f) {
                    int b = (int)(s * 1024.0f);
                    b = b < 0 ? 0 : (b > NBINS - 1 ? NBINS - 1 : b);
                    if (b >= lo && b < hi) {
                        int p = atomicAdd(&s_cnt, 1);
                        if (p < CAP) {
                            uint32_t bits = __float_as_uint(s);
                            keys[p] = ((uint64_t)(~bits) << 16) | (uint64_t)(4 * q + u);
                        }
                    }
                }
            }
        }
        __syncthreads();
        const int M = min(s_cnt, CAP);
        for (int p = tid; p < CAP; p += TPB)
            if (p >= M) keys[p] = ~0ull;
        __syncthreads();
        for (int k = 2; k <= CAP; k <<= 1)
            for (int j = k >> 1; j > 0; j >>= 1) {
                int t = tid, ixj = t ^ j;
                if (ixj > t) {
                    uint64_t a = keys[t], b = keys[ixj];
                    if ((a > b) == ((t & k) == 0)) { keys[t] = b; keys[ixj] = a; }
                }
                __syncthreads();
            }
        if (tid < M) {
            uint64_t key = keys[tid];
            int n = (int)(key & 0xFFFFull);
            uint32_t bits = ~((uint32_t)(key >> 16));
            float4 bx = *(const float4*)(boxes + (size_t)n * 4);
            rbox[tid] = bx;
            ra[tid] = (bx.z - bx.x) * (bx.w - bx.y);
            rs[tid] = __uint_as_float(bits);
        }
        __syncthreads();
        {
            bool alive = (tid < M);
            if (alive) {
                float4 b = rbox[tid]; float arb = ra[tid];
                for (int k2 = 0; k2 < kc; k2++) {
                    float4 kb = kbox[k2];
                    float ix1 = fmaxf(kb.x, b.x), iy1 = fmaxf(kb.y, b.y);
                    float ix2 = fminf(kb.z, b.z), iy2 = fminf(kb.w, b.w);
                    float inter = fmaxf(ix2 - ix1, 0.0f) * fmaxf(iy2 - iy1, 0.0f);
                    float iou = inter / (kar[k2] + arb - inter + 1e-8f);
                    if (iou > 0.5f) { alive = false; break; }
                }
            }
            uint64_t bal = __ballot(alive);
            if ((tid & 63) == 0) lw[tid >> 6] = bal;
        }
        __syncthreads();
        {
            const int wid = tid >> 6, lane = tid & 63;
            const int MW = (M + 63) >> 6;
            for (int i = wid; i < M; i += TPB / 64) {
                float4 bi = rbox[i]; float ari = ra[i];
                for (int w = i >> 6; w < MW; w++) {
                    int jj = (w << 6) + lane;
                    bool bit = false;
                    if (jj > i && jj < M) {
                        float4 bj = rbox[jj];
                        float ix1 = fmaxf(bi.x, bj.x), iy1 = fmaxf(bi.y, bj.y);
                        float ix2 = fminf(bi.z, bj.z), iy2 = fminf(bi.w, bj.w);
                        float inter = fmaxf(ix2 - ix1, 0.0f) * fmaxf(iy2 - iy1, 0.0f);
                        float iou = inter / (ari + ra[jj] - inter + 1e-8f);
                        bit = iou > 0.5f;
                    }
                    uint64_t bal = __ballot(bit);
                    if (lane == 0) smat[i * 8 + w] = bal;
                }
            }
        }
        __syncthreads();
        if (tid == 0) {
            int kcl = kc;
            const int MW = (M + 63) >> 6;
            for (int w = 0; w < MW && kcl < KDET; w++) {
                uint64_t lv = lw[w];
                const int base = w << 6;
                while (lv) {
                    int b = __ffsll((unsigned long long)lv) - 1;
                    lv &= lv - 1;
                    int i = base + b;
                    if (i >= M) break;
                    kbox[kcl] = rbox[i]; kar[kcl] = ra[i]; ksc[kcl] = rs[i];
                    kcl++;
                    if (kcl == KDET) break;
                    lv &= ~smat[i * 8 + w];
                    for (int ww = w + 1; ww < MW; ww++) {
                        uint64_t r = smat[i * 8 + ww];
                        if (r) lw[ww] &= ~r;
                    }
                }
            }
            s_kc = kcl;
        }
        __syncthreads();
        kc = s_kc;
        hi = lo;
    }
    __syncthreads();

    float* o_sc = out;
    float* o_cl = out + NCLS * KDET;
    float* o_bx = out + 2 * NCLS * KDET;
    float* o_va = out + 6 * NCLS * KDET;
    for (int k = tid; k < KDET; k += TPB) {
        bool valid = k < kc;
        o_sc[c * KDET + k] = valid ? ksc[k] : 0.0f;
        o_cl[c * KDET + k] = (float)c;
        o_va[c * KDET + k] = valid ? 1.0f : 0.0f;
        float4 bo;
        if (valid) bo = kbox[k];
        else { bo.x = 0.0f; bo.y = 0.0f; bo.z = 0.0f; bo.w = 0.0f; }
        *(float4*)(o_bx + ((size_t)(c * KDET + k)) * 4) = bo;
    }
}

extern "C" void kernel_launch(void* const* d_in, const int* in_sizes, int n_in,
                              void* d_out, int out_size, void* d_ws, size_t ws_size,
                              hipStream_t stream) {
    const float* scores = (const float*)d_in[0];   // [N, C] f32
    const float* boxes  = (const float*)d_in[1];   // [N, 4] f32
    float* out = (float*)d_out;                    // 56000 f32: scores|classes|boxes|valids

    float* st = (float*)d_ws;
    const int tblocks = (N_ANCH + TROWS - 1) / TROWS;
    transpose_scores<<<tblocks, 256, 0, stream>>>(scores, st);

    if (ws_size >= WS_NEED) {
        int*      hpart = (int*)((char*)d_ws + HPART_OFF);
        int*      cnt   = (int*)((char*)d_ws + CNT_OFF);
        uint64_t* list  = (uint64_t*)((char*)d_ws + LIST_OFF);
        hist_kernel<<<NCLS * NSEG, 256, 0, stream>>>(st, hpart, cnt);
        collect_kernel<<<NCLS * NSEG, 256, 0, stream>>>(st, hpart, cnt, list);
        nms_final<<<NCLS, TPB, 0, stream>>>(st, boxes, hpart, cnt, list, out);
    } else {
        nms_mono<<<NCLS, TPB, 0, stream>>>(st, boxes, out);   // proven-exact round-2 path
    }
}

// Round 4
// 133.076 us; speedup vs baseline: 2.1714x; 2.1714x over previous
//
#include <hip/hip_runtime.h>
#include <math.h>
#include <stdint.h>

#define N_ANCH 49104
#define NCLS 80
#define KDET 100
#define CAP 256              // sort size == TPB; candidates per chunk
#define TPB 256
#define NBINS 1024
#define NBLK 240             // collect blocks
#define SUBCAP 32            // slots per (class, block) sub-list; expected ~0.8 used
#define THETA 0.996090f      // targets ~192 candidates/class; exact fallback if wrong
#define QTOT (N_ANCH * NCLS / 4)   // 982080 float4 quads
#define QPB (QTOT / NBLK)          // 4092 (exact)

// ws layout: list [NCLS*NBLK*SUBCAP u64] | subcnt [NCLS*NBLK int]
#define LIST_ELEMS ((size_t)NCLS * NBLK * SUBCAP)
#define SUBCNT_OFF (LIST_ELEMS * 8)
#define WS_NEED (SUBCNT_OFF + (size_t)NCLS * NBLK * 4)

// ---------------- 240 blocks: contiguous read of [N,C], LDS-counter pushes, NO global atomics ----------------
__global__ __launch_bounds__(TPB) void collect_kernel(const float* __restrict__ scores,
                                                      uint64_t* __restrict__ list,
                                                      int* __restrict__ subcnt) {
    const int blk = blockIdx.x, tid = threadIdx.x;
    __shared__ int lcnt[NCLS];
    for (int c = tid; c < NCLS; c += TPB) lcnt[c] = 0;
    __syncthreads();
    const float4* sc4 = (const float4*)scores;
    const int q0 = blk * QPB;
    for (int q = q0 + tid; q < q0 + QPB; q += TPB) {
        float4 v = sc4[q];
        int n = q / 20;             // anchor: 4q/80
        int c0 = 4 * (q % 20);      // first class of this quad (80 % 4 == 0: never crosses anchors)
        float ss[4] = {v.x, v.y, v.z, v.w};
#pragma unroll
        for (int u = 0; u < 4; u++) {
            float s = ss[u];
            if (s > THETA) {
                int c = c0 + u;
                int p = atomicAdd(&lcnt[c], 1);          // LDS atomic only
                if (p < SUBCAP) {
                    uint32_t bits = __float_as_uint(s);  // s>0: bit order == value order
                    list[((size_t)c * NBLK + blk) * SUBCAP + p] =
                        ((uint64_t)(~bits) << 16) | (uint64_t)n;   // sort key: score desc, anchor asc
                }
            }
        }
    }
    __syncthreads();
    for (int c = tid; c < NCLS; c += TPB) subcnt[c * NBLK + blk] = lcnt[c];  // raw (overflow detectable)
}

// ---------------- shared state for the per-class core ----------------
struct ChunkShared {
    uint64_t keys[CAP];
    float4   rbox[CAP];
    float    ra[CAP], rs[CAP];
    uint64_t smat[CAP * (CAP / 64)];   // suppressor rows (j > i only)
    uint64_t lwbuf[CAP / 64];
    float4   kbox[KDET];
    float    kar[KDET], ksc[KDET];
    int      kidx[KDET];
    int      s_kc;
};

// sort -> gather -> filter-vs-kept -> bitmatrix -> register-mask scan -> copy keeps. Exact.
__device__ __forceinline__ int process_chunk(ChunkShared& S, int tid, int M, int kc,
                                             const float* __restrict__ boxes) {
    // bitonic sort ascending over packed keys (TPB == CAP: one slot per thread)
    for (int k = 2; k <= CAP; k <<= 1)
        for (int j = k >> 1; j > 0; j >>= 1) {
            int ixj = tid ^ j;
            if (ixj > tid) {
                uint64_t a = S.keys[tid], b = S.keys[ixj];
                if ((a > b) == ((tid & k) == 0)) { S.keys[tid] = b; S.keys[ixj] = a; }
            }
            __syncthreads();
        }
    if (tid < M) {
        uint64_t key = S.keys[tid];
        int n = (int)(key & 0xFFFFull);                  // N_ANCH < 65536
        float4 bx = *(const float4*)(boxes + (size_t)n * 4);
        S.rbox[tid] = bx;
        S.ra[tid] = (bx.z - bx.x) * (bx.w - bx.y);
        S.rs[tid] = __uint_as_float(~((uint32_t)(key >> 16)));
    }
    __syncthreads();
    // filter vs previously-kept boxes (exact chunk continuation); live mask via ballot
    {
        bool alive = (tid < M);
        if (alive && kc > 0) {
            float4 b = S.rbox[tid];
            float arb = S.ra[tid];
            for (int k2 = 0; k2 < kc; k2++) {
                float4 kb = S.kbox[k2];
                float ix1 = fmaxf(kb.x, b.x), iy1 = fmaxf(kb.y, b.y);
                float ix2 = fminf(kb.z, b.z), iy2 = fminf(kb.w, b.w);
                float inter = fmaxf(ix2 - ix1, 0.0f) * fmaxf(iy2 - iy1, 0.0f);
                float iou = inter / (S.kar[k2] + arb - inter + 1e-8f);
                if (iou > 0.5f) { alive = false; break; }
            }
        }
        uint64_t bal = __ballot(alive);
        if ((tid & 63) == 0) S.lwbuf[tid >> 6] = bal;
    }
    __syncthreads();
    // bitmatrix: row i = "i suppresses j" bits for j > i (wave-parallel ballots)
    const int MW = (M + 63) >> 6;
    {
        const int wid = tid >> 6, lane = tid & 63;
        for (int i = wid; i < M; i += TPB / 64) {
            float4 bi = S.rbox[i];                        // same-address LDS broadcast
            float ari = S.ra[i];
            for (int w = i >> 6; w < MW; w++) {
                int jj = (w << 6) + lane;
                bool bit = false;
                if (jj > i && jj < M) {
                    float4 bj = S.rbox[jj];
                    float ix1 = fmaxf(bi.x, bj.x), iy1 = fmaxf(bi.y, bj.y);
                    float ix2 = fminf(bi.z, bj.z), iy2 = fminf(bi.w, bj.w);
                    float inter = fmaxf(ix2 - ix1, 0.0f) * fmaxf(iy2 - iy1, 0.0f);
                    float iou = inter / (ari + S.ra[jj] - inter + 1e-8f);
                    bit = iou > 0.5f;
                }
                uint64_t bb = __ballot(bit);
                if (lane == 0) S.smat[(size_t)i * (CAP / 64) + w] = bb;
            }
        }
    }
    __syncthreads();
    // serial scan, live mask in 4 registers; rows masked below selected word (no live j < i exists)
    const int kc0 = kc;
    if (tid == 0) {
        uint64_t L0 = S.lwbuf[0], L1 = S.lwbuf[1], L2 = S.lwbuf[2], L3 = S.lwbuf[3];
        int k2 = kc;
        while (k2 < KDET) {
            int i;
            if (L0)      i = __ffsll((unsigned long long)L0) - 1;
            else if (L1) i = 64  + __ffsll((unsigned long long)L1) - 1;
            else if (L2) i = 128 + __ffsll((unsigned long long)L2) - 1;
            else if (L3) i = 192 + __ffsll((unsigned long long)L3) - 1;
            else break;
            S.kidx[k2++] = i;
            const int wlo = i >> 6;
            const uint64_t bit = 1ull << (i & 63);
            if (wlo == 0) L0 &= ~bit; else if (wlo == 1) L1 &= ~bit;
            else if (wlo == 2) L2 &= ~bit; else L3 &= ~bit;
            if (k2 >= KDET) break;
            const uint64_t* row = &S.smat[(size_t)i * (CAP / 64)];
            uint64_t r0 = row[0], r1 = row[1], r2 = row[2], r3 = row[3];
            if (wlo <= 0) L0 &= ~r0;          // words < wlo are stale (rows cover j > i only) -> masked
            if (wlo <= 1) L1 &= ~r1;
            if (wlo <= 2) L2 &= ~r2;
            if (wlo <= 3) L3 &= ~r3;
        }
        S.s_kc = k2;
    }
    __syncthreads();
    const int nkc = S.s_kc;
    for (int k = kc0 + tid; k < nkc; k += TPB) {   // parallel copy of new keeps (off scan critical path)
        int i = S.kidx[k];
        S.kbox[k] = S.rbox[i];
        S.kar[k] = S.ra[i];
        S.ksc[k] = S.rs[i];
    }
    __syncthreads();
    return nkc;
}

// ---------------- 80 blocks: gather sub-lists -> core; exact strided fallback if heuristics miss ----------------
__global__ __launch_bounds__(TPB) void nms_final(const float* __restrict__ scores,
                                                 const float* __restrict__ boxes,
                                                 const uint64_t* __restrict__ list,
                                                 const int* __restrict__ subcnt,
                                                 int use_lists,
                                                 float* __restrict__ out) {
    const int c = blockIdx.x, tid = threadIdx.x;
    __shared__ ChunkShared S;
    __shared__ int cnts[NBLK];
    __shared__ int pref[TPB];
    __shared__ int hist[NBINS];
    __shared__ int s_ov, s_cnt, s_lo;

    int kc = 0;
    bool fast = false;
    if (use_lists) {
        for (int t = tid; t < NBLK; t += TPB) cnts[t] = subcnt[c * NBLK + t];
        if (tid == 0) s_ov = 0;
        __syncthreads();
        int v = (tid < NBLK) ? cnts[tid] : 0;
        if (v > SUBCAP) atomicOr(&s_ov, 1);
        pref[tid] = (tid < NBLK) ? min(v, SUBCAP) : 0;
        __syncthreads();
        for (int d = 1; d < TPB; d <<= 1) {            // Hillis-Steele inclusive scan
            int val = pref[tid];
            int add = (tid >= d) ? pref[tid - d] : 0;
            __syncthreads();
            pref[tid] = val + add;
            __syncthreads();
        }
        const int M0 = pref[TPB - 1];
        fast = (s_ov == 0) && (M0 <= CAP);
        __syncthreads();
        if (fast) {
            if (tid < NBLK) {
                int nct = cnts[tid];                   // <= SUBCAP (no overflow on fast path)
                int off = pref[tid] - nct;
                const uint64_t* src = list + ((size_t)c * NBLK + tid) * SUBCAP;
                for (int k = 0; k < nct; k++) S.keys[off + k] = src[k];
            }
            __syncthreads();
            if (tid >= M0) S.keys[tid] = ~0ull;        // pad (TPB == CAP)
            __syncthreads();
            kc = process_chunk(S, tid, M0, 0, boxes);
        }
    }
    if (kc < KDET) {
        // exact slow path: strided column reads; partition s <= THETA iff fast chunk consumed (s > THETA)
        const float hicut = fast ? THETA : 3.0e38f;
        if (!fast) kc = 0;
        for (int b = tid; b < NBINS; b += TPB) hist[b] = 0;
        __syncthreads();
        for (int n = tid; n < N_ANCH; n += TPB) {
            float s = scores[(size_t)n * NCLS + c];
            if (s > 0.05f && s <= hicut) {
                int b = (int)(s * 1024.0f);
                b = b < 0 ? 0 : (b > NBINS - 1 ? NBINS - 1 : b);
                atomicAdd(&hist[b], 1);
            }
        }
        __syncthreads();
        int hi = NBINS;
        while (hi > 0 && kc < KDET) {
            if (tid == 0) {
                int lo = hi, tot = 0;
                while (lo > 0 && tot + hist[lo - 1] <= CAP) { lo--; tot += hist[lo]; }
                if (lo == hi) lo = hi - 1;             // oversized single bin (~48 expected): truncate
                s_lo = lo; s_cnt = 0;
            }
            __syncthreads();
            const int lo = s_lo;
            for (int n = tid; n < N_ANCH; n += TPB) {
                float s = scores[(size_t)n * NCLS + c];
                if (s > 0.05f && s <= hicut) {
                    int b = (int)(s * 1024.0f);
                    b = b < 0 ? 0 : (b > NBINS - 1 ? NBINS - 1 : b);
                    if (b >= lo && b < hi) {
                        int p = atomicAdd(&s_cnt, 1);
                        if (p < CAP) {
                            uint32_t bits = __float_as_uint(s);
                            S.keys[p] = ((uint64_t)(~bits) << 16) | (uint64_t)n;
                        }
                    }
                }
            }
            __syncthreads();
            const int M2 = min(s_cnt, CAP);
            if (tid >= M2) S.keys[tid] = ~0ull;
            __syncthreads();
            kc = process_chunk(S, tid, M2, kc, boxes);
            hi = lo;
        }
    }
    __syncthreads();

    // outputs: [scores | classes | boxes | valids] as float32
    float* o_sc = out;
    float* o_cl = out + NCLS * KDET;
    float* o_bx = out + 2 * NCLS * KDET;
    float* o_va = out + 6 * NCLS * KDET;
    for (int k = tid; k < KDET; k += TPB) {
        bool valid = k < kc;
        o_sc[c * KDET + k] = valid ? S.ksc[k] : 0.0f;
        o_cl[c * KDET + k] = (float)c;
        o_va[c * KDET + k] = valid ? 1.0f : 0.0f;
        float4 bo;
        if (valid) bo = S.kbox[k];
        else { bo.x = 0.0f; bo.y = 0.0f; bo.z = 0.0f; bo.w = 0.0f; }
        *(float4*)(o_bx + ((size_t)(c * KDET + k)) * 4) = bo;
    }
}

extern "C" void kernel_launch(void* const* d_in, const int* in_sizes, int n_in,
                              void* d_out, int out_size, void* d_ws, size_t ws_size,
                              hipStream_t stream) {
    const float* scores = (const float*)d_in[0];   // [N, C] f32
    const float* boxes  = (const float*)d_in[1];   // [N, 4] f32
    float* out = (float*)d_out;                    // 56000 f32: scores|classes|boxes|valids

    uint64_t* list   = (uint64_t*)d_ws;
    int*      subcnt = (int*)((char*)d_ws + SUBCNT_OFF);
    const int use_lists = (ws_size >= WS_NEED) ? 1 : 0;

    if (use_lists) {
        collect_kernel<<<NBLK, TPB, 0, stream>>>(scores, list, subcnt);
    }
    nms_final<<<NCLS, TPB, 0, stream>>>(scores, boxes, list, subcnt, use_lists, out);
}